// Round 4
// baseline (195.733 us; speedup 1.0000x reference)
//
#include <hip/hip_runtime.h>

// B=8, C=16, H=W=384. Inputs (fp32): net_out, target, max_positiones.
// loss_bc = 0.05*m1/(d1+eps) + 0.95*m2/(d2+eps)
//   m1 = sum(d2*t), d1 = sum(t), m2 = sum(d2) - m1, d2den = HW - d1
// active_bc = !(max(t)==0 && max(mp)==0) -> mp scanned only if max(t)==0 (rare, final kernel)
// img_loss_b = sum_c(losses)/count_nonzero(losses); out = mean_b.
//
// R4: async global->LDS staging (global_load_lds dwordx4). R1-R3 showed the
// compiler serializes register-destination loads (VGPR 32-40, one 1KB
// wave-load per ~230cy/CU, 2.75 TB/s). Async LDS loads have no register
// dependence until the single vmcnt(0), so 18 transfers/thread stay in flight.

#define B_DIM 8
#define C_DIM 16
#define BC    (B_DIM * C_DIM)        // 128
#define HW    147456                 // 384*384
#define SEGS  32
#define SEG_ELEMS (HW / SEGS)        // 4608
#define SEG_F4    (SEG_ELEMS / 4)    // 1152
#define TPB   128
#define F4PT  (SEG_F4 / TPB)         // 9 float4 per thread per array
#define NBLK  (BC * SEGS)            // 4096

#define ALPHA  0.05f
#define SMOOTH 1e-6f

typedef const __attribute__((address_space(1))) unsigned int* gptr_t;
typedef __attribute__((address_space(3))) unsigned int* lptr_t;

// ws layout: float4 per block: {sum_t, m1, sum_d2, mx_t}

__global__ __launch_bounds__(TPB) void mismatch_passA(
    const float* __restrict__ net_out,
    const float* __restrict__ target,
    float4* __restrict__ ws)
{
    __shared__ float4 t_lds[SEG_F4];   // 18432 B
    __shared__ float4 n_lds[SEG_F4];   // 18432 B
    __shared__ float s[2][4];

    const int blk = blockIdx.x;                       // [0, NBLK)
    const size_t base4 = (size_t)blk * SEG_F4;
    const int tid = threadIdx.x;

    const float4* t4 = (const float4*)target + base4;
    const float4* n4 = (const float4*)net_out + base4;

    // Async staging: 18 fire-and-forget 16B-per-lane transfers per thread.
    // LDS dest is wave-uniform base + lane*16; idx = k*TPB + tid keeps each
    // wave's 64 lanes contiguous in both global and LDS space.
#pragma unroll
    for (int k = 0; k < F4PT; ++k) {
        const int idx = k * TPB + tid;
        __builtin_amdgcn_global_load_lds((gptr_t)(t4 + idx), (lptr_t)(t_lds + idx), 16, 0, 0);
    }
#pragma unroll
    for (int k = 0; k < F4PT; ++k) {
        const int idx = k * TPB + tid;
        __builtin_amdgcn_global_load_lds((gptr_t)(n4 + idx), (lptr_t)(n_lds + idx), 16, 0, 0);
    }

    asm volatile("s_waitcnt vmcnt(0)" ::: "memory");
    __syncthreads();

    float sum_t = 0.f, m1 = 0.f, sd2 = 0.f, mxt = 0.f;
#pragma unroll
    for (int k = 0; k < F4PT; ++k) {
        const int idx = k * TPB + tid;
        const float4 tv = t_lds[idx];
        const float4 nv = n_lds[idx];
#define ACC(c) { float t = tv.c, n = nv.c;                \
                 float d = t - n; float d2 = d * d;       \
                 sum_t += t; sd2 += d2;                   \
                 m1 = fmaf(d2, t, m1); mxt = fmaxf(mxt, t); }
        ACC(x) ACC(y) ACC(z) ACC(w)
#undef ACC
    }

    // wave (64-lane) reduction
#pragma unroll
    for (int off = 32; off > 0; off >>= 1) {
        sum_t += __shfl_down(sum_t, off);
        m1    += __shfl_down(m1, off);
        sd2   += __shfl_down(sd2, off);
        mxt    = fmaxf(mxt, __shfl_down(mxt, off));
    }

    const int wave = tid >> 6, lane = tid & 63;
    if (lane == 0) { s[wave][0] = sum_t; s[wave][1] = m1; s[wave][2] = sd2; s[wave][3] = mxt; }
    __syncthreads();
    if (tid == 0) {
        float4 o;
        o.x = s[0][0] + s[1][0];
        o.y = s[0][1] + s[1][1];
        o.z = s[0][2] + s[1][2];
        o.w = fmaxf(s[0][3], s[1][3]);
        ws[blk] = o;
    }
}

__global__ __launch_bounds__(128) void mismatch_final(
    const float4* __restrict__ ws,
    const float* __restrict__ maxp,
    float* __restrict__ out)
{
    __shared__ float losses[BC];
    __shared__ float img[B_DIM];
    const int tid = threadIdx.x;   // one thread per (b,c) slice

    {
        float sum_t = 0.f, m1 = 0.f, sd2 = 0.f, mxt = 0.f;
#pragma unroll
        for (int s = 0; s < SEGS; ++s) {
            const float4 v = ws[(tid << 5) + s];
            sum_t += v.x; m1 += v.y; sd2 += v.z; mxt = fmaxf(mxt, v.w);
        }
        bool inactive = false;
        if (mxt == 0.f) {
            // Rare path: slice's target is all-zero; must consult max_positiones.
            const float4* m4 = (const float4*)maxp + (size_t)tid * (HW / 4);
            float mx = 0.f;
            for (int i = 0; i < HW / 4; ++i) {
                const float4 v = m4[i];
                mx = fmaxf(mx, fmaxf(fmaxf(v.x, v.y), fmaxf(v.z, v.w)));
            }
            inactive = (mx == 0.f);
        }
        const float m2 = sd2 - m1;
        const float d1 = sum_t;
        const float d2 = (float)HW - sum_t;
        const float loss = ALPHA * m1 / (d1 + SMOOTH)
                         + (1.f - ALPHA) * m2 / (d2 + SMOOTH);
        losses[tid] = inactive ? 0.f : loss;
    }
    __syncthreads();
    if (tid < B_DIM) {
        float s = 0.f; int cnt = 0;
#pragma unroll
        for (int c = 0; c < C_DIM; ++c) {
            const float l = losses[tid * C_DIM + c];
            s += l;
            cnt += (l != 0.f) ? 1 : 0;
        }
        img[tid] = s / (float)cnt;   // 0/0 -> NaN matches reference
    }
    __syncthreads();
    if (tid == 0) {
        float s = 0.f;
#pragma unroll
        for (int b = 0; b < B_DIM; ++b) s += img[b];
        out[0] = s / (float)B_DIM;
    }
}

extern "C" void kernel_launch(void* const* d_in, const int* in_sizes, int n_in,
                              void* d_out, int out_size, void* d_ws, size_t ws_size,
                              hipStream_t stream) {
    const float* net_out = (const float*)d_in[0];
    const float* target  = (const float*)d_in[1];
    const float* maxp    = (const float*)d_in[2];
    float* out = (float*)d_out;
    float4* ws = (float4*)d_ws;   // needs NBLK*16 = 64 KB

    mismatch_passA<<<NBLK, TPB, 0, stream>>>(net_out, target, ws);
    mismatch_final<<<1, 128, 0, stream>>>(ws, maxp, out);
}

// Round 6
// 185.081 us; speedup vs baseline: 1.0576x; 1.0576x over previous
//
#include <hip/hip_runtime.h>

// B=8, C=16, H=W=384. Inputs (fp32): net_out, target, max_positiones.
// loss_bc = 0.05*m1/(d1+eps) + 0.95*m2/(d2+eps)
//   m1 = sum(d2*t), d1 = sum(t), m2 = sum(d2) - m1, d2den = HW - d1
// active_bc = !(max(t)==0 && max(mp)==0) -> mp scanned only if max(t)==0 (rare, final kernel)
// img_loss_b = sum_c(losses)/count_nonzero(losses); out = mean_b.
//
// R6 = R5 with the compile fix: __builtin_nontemporal_load needs a clang
// ext_vector type, not HIP_vector_type. Theory unchanged: R1-R4 showed a
// structure-insensitive cap time = N_waveloads * 95ns/CU (4.5 B/cy/CU),
// identical for sync VGPR loads, async LDS loads, warm or cold cache.
// nt loads bypass L1/L2 line allocation for these zero-reuse streams.

typedef float f32x4 __attribute__((ext_vector_type(4)));

#define B_DIM 8
#define C_DIM 16
#define BC    (B_DIM * C_DIM)        // 128
#define HW    147456                 // 384*384
#define SEGS  16
#define SEG_ELEMS (HW / SEGS)        // 9216
#define TPB   256
#define F4PT  (SEG_ELEMS / 4 / TPB)  // 9 float4 per thread per array
#define NBLK  (BC * SEGS)            // 2048

#define ALPHA  0.05f
#define SMOOTH 1e-6f

// ws layout: float4 per block: {sum_t, m1, sum_d2, mx_t}

__global__ __launch_bounds__(TPB, 2) void mismatch_passA(
    const float* __restrict__ net_out,
    const float* __restrict__ target,
    float4* __restrict__ ws)
{
    const int blk = blockIdx.x;                       // [0, NBLK)
    const size_t base4 = (size_t)blk * (SEG_ELEMS / 4);
    const int tid = threadIdx.x;

    const f32x4* __restrict__ t4 = (const f32x4*)target + base4;
    const f32x4* __restrict__ n4 = (const f32x4*)net_out + base4;

    float sum_t = 0.f, m1 = 0.f, sd2 = 0.f, mxt = 0.f;

#pragma unroll
    for (int k = 0; k < F4PT; ++k) {
        const int idx = k * TPB + tid;   // coalesced float4 access
        const f32x4 tv = __builtin_nontemporal_load(t4 + idx);
        const f32x4 nv = __builtin_nontemporal_load(n4 + idx);
#define ACC(c) { float t = tv.c, n = nv.c;                \
                 float d = t - n; float d2 = d * d;       \
                 sum_t += t; sd2 += d2;                   \
                 m1 = fmaf(d2, t, m1); mxt = fmaxf(mxt, t); }
        ACC(x) ACC(y) ACC(z) ACC(w)
#undef ACC
    }

    // wave (64-lane) reduction
#pragma unroll
    for (int off = 32; off > 0; off >>= 1) {
        sum_t += __shfl_down(sum_t, off);
        m1    += __shfl_down(m1, off);
        sd2   += __shfl_down(sd2, off);
        mxt    = fmaxf(mxt, __shfl_down(mxt, off));
    }

    __shared__ float s[4][4];
    const int wave = tid >> 6, lane = tid & 63;
    if (lane == 0) { s[wave][0] = sum_t; s[wave][1] = m1; s[wave][2] = sd2; s[wave][3] = mxt; }
    __syncthreads();
    if (tid == 0) {
        float4 o;
        o.x = s[0][0] + s[1][0] + s[2][0] + s[3][0];
        o.y = s[0][1] + s[1][1] + s[2][1] + s[3][1];
        o.z = s[0][2] + s[1][2] + s[2][2] + s[3][2];
        o.w = fmaxf(fmaxf(s[0][3], s[1][3]), fmaxf(s[2][3], s[3][3]));
        ws[blk] = o;
    }
}

__global__ __launch_bounds__(128) void mismatch_final(
    const float4* __restrict__ ws,
    const float* __restrict__ maxp,
    float* __restrict__ out)
{
    __shared__ float losses[BC];
    __shared__ float img[B_DIM];
    const int tid = threadIdx.x;   // one thread per (b,c) slice

    {
        float sum_t = 0.f, m1 = 0.f, sd2 = 0.f, mxt = 0.f;
#pragma unroll
        for (int s = 0; s < SEGS; ++s) {
            const float4 v = ws[(tid << 4) + s];
            sum_t += v.x; m1 += v.y; sd2 += v.z; mxt = fmaxf(mxt, v.w);
        }
        bool inactive = false;
        if (mxt == 0.f) {
            // Rare path: slice's target is all-zero; must consult max_positiones.
            const float4* m4 = (const float4*)maxp + (size_t)tid * (HW / 4);
            float mx = 0.f;
            for (int i = 0; i < HW / 4; ++i) {
                const float4 v = m4[i];
                mx = fmaxf(mx, fmaxf(fmaxf(v.x, v.y), fmaxf(v.z, v.w)));
            }
            inactive = (mx == 0.f);
        }
        const float m2 = sd2 - m1;
        const float d1 = sum_t;
        const float d2 = (float)HW - sum_t;
        const float loss = ALPHA * m1 / (d1 + SMOOTH)
                         + (1.f - ALPHA) * m2 / (d2 + SMOOTH);
        losses[tid] = inactive ? 0.f : loss;
    }
    __syncthreads();
    if (tid < B_DIM) {
        float s = 0.f; int cnt = 0;
#pragma unroll
        for (int c = 0; c < C_DIM; ++c) {
            const float l = losses[tid * C_DIM + c];
            s += l;
            cnt += (l != 0.f) ? 1 : 0;
        }
        img[tid] = s / (float)cnt;   // 0/0 -> NaN matches reference
    }
    __syncthreads();
    if (tid == 0) {
        float s = 0.f;
#pragma unroll
        for (int b = 0; b < B_DIM; ++b) s += img[b];
        out[0] = s / (float)B_DIM;
    }
}

extern "C" void kernel_launch(void* const* d_in, const int* in_sizes, int n_in,
                              void* d_out, int out_size, void* d_ws, size_t ws_size,
                              hipStream_t stream) {
    const float* net_out = (const float*)d_in[0];
    const float* target  = (const float*)d_in[1];
    const float* maxp    = (const float*)d_in[2];
    float* out = (float*)d_out;
    float4* ws = (float4*)d_ws;   // needs NBLK*16 = 32 KB

    mismatch_passA<<<NBLK, TPB, 0, stream>>>(net_out, target, ws);
    mismatch_final<<<1, 128, 0, stream>>>(ws, maxp, out);
}